// Round 1
// 759.078 us; speedup vs baseline: 1.0730x; 1.0730x over previous
//
#include <hip/hip_runtime.h>
#include <hip/hip_bf16.h>
#include <math.h>

// Starcoder2 attention R5:
//  - NEW: fp32->bf16 pre-conversion kernels for hidden/wqkv/wo; GEMMs now
//    take bf16 operands and stage via __builtin_amdgcn_global_load_lds
//    (dwordx4, zero VALU staging) -- the m97 structure (874-912 TF verified
//    on gfx950 vs ~420 TF for the previous VALU-packed staging).
//  - attn writes its output directly as bf16 (identical numerics: GEMM2
//    staging RNE-converted to bf16 anyway), halving GEMM2 A-fetch.
//  - Attention MFMA flash kernel otherwise unchanged from verified R4.
// T=2048, HID=4608, H=36, KV=4, D=128, window=1024.

#define T_SEQ   2048
#define HIDDEN  4608
#define NHEAD   36
#define NKVH    4
#define HEADDIM 128
#define GQA_G   9
#define NQKV    5632
#define KOFF    4608
#define VOFF    5120
#define NEG_BIG -1e30f

typedef short bf16x8 __attribute__((ext_vector_type(8)));
typedef float f32x4  __attribute__((ext_vector_type(4)));

// pack 8 fp32 -> 8 bf16 (RNE)
__device__ inline bf16x8 pack8(float4 u, float4 v) {
    union { bf16x8 v8; __hip_bfloat162 h[4]; } r;
    r.h[0] = __float22bfloat162_rn(make_float2(u.x, u.y));
    r.h[1] = __float22bfloat162_rn(make_float2(u.z, u.w));
    r.h[2] = __float22bfloat162_rn(make_float2(v.x, v.y));
    r.h[3] = __float22bfloat162_rn(make_float2(v.z, v.w));
    return r.v8;
}

// async global->LDS, 16 B per lane. LDS dest must be wave-uniform; HW writes
// lane l at ldsbase + l*16.
typedef const __attribute__((address_space(1))) int* gas_ptr;
typedef __attribute__((address_space(3))) int*       las_ptr;
__device__ __forceinline__ void gload_lds16(const void* g, void* l) {
    __builtin_amdgcn_global_load_lds((gas_ptr)g, (las_ptr)l, 16, 0, 0);
}

// ---------------------------------------------------------------------------
// fp32 -> bf16 conversion (memory-bound, vectorized 8 elems/thread/iter)
// ---------------------------------------------------------------------------
__global__ __launch_bounds__(256)
void cvt_bf16_kernel(const float* __restrict__ in, __hip_bfloat16* __restrict__ out,
                     int n8)
{
    for (int i = blockIdx.x * 256 + threadIdx.x; i < n8; i += gridDim.x * 256) {
        const float4 a = *(const float4*)(in + (size_t)i * 8);
        const float4 b = *(const float4*)(in + (size_t)i * 8 + 4);
        *(bf16x8*)(out + (size_t)i * 8) = pack8(a, b);
    }
}

// ---------------------------------------------------------------------------
// GEMM: C[M,N](fp32) = A[M,K](bf16) @ B[N,K](bf16)^T + bias
// 128x128 tile, BK=32, 4 waves, global_load_lds staging (m97 structure).
// ---------------------------------------------------------------------------
__global__ __launch_bounds__(256)
void gemm_bf16bt_kernel(const __hip_bfloat16* __restrict__ A,
                        const __hip_bfloat16* __restrict__ B,
                        const float* __restrict__ bias,
                        float* __restrict__ C, int N, int K)
{
    __shared__ short As[128 * 32];   // 8 KB, row-major [row][k], 64 B rows
    __shared__ short Bs[128 * 32];   // 8 KB

    const int tid  = threadIdx.x;
    const int lane = tid & 63;
    const int wave = tid >> 6;
    const int row0 = blockIdx.y * 128;
    const int col0 = blockIdx.x * 128;
    const int wr   = (wave >> 1) * 64;
    const int wc   = (wave & 1) * 64;
    const int fr   = lane & 15;
    const int fk   = (lane >> 4) * 8;

    // staging map: wave w covers rows [w*32, w*32+32) in two 16-row chunks;
    // lane l -> row w*32 + c*16 + (l>>2), col (l&3)*8.  LDS byte offset of
    // lane l within chunk = l*16 -> identical row-major layout.
    const int srow = lane >> 2;
    const int scol = (lane & 3) * 8;

    const __hip_bfloat16* Ag0 = A + (size_t)(row0 + wave * 32 + srow) * K + scol;
    const __hip_bfloat16* Ag1 = Ag0 + (size_t)16 * K;
    const __hip_bfloat16* Bg0 = B + (size_t)(col0 + wave * 32 + srow) * K + scol;
    const __hip_bfloat16* Bg1 = Bg0 + (size_t)16 * K;

    short* Al0 = &As[(wave * 32) * 32];        // wave-uniform LDS bases
    short* Al1 = &As[(wave * 32 + 16) * 32];
    short* Bl0 = &Bs[(wave * 32) * 32];
    short* Bl1 = &Bs[(wave * 32 + 16) * 32];

    f32x4 acc[4][4];
    #pragma unroll
    for (int i = 0; i < 4; ++i)
        #pragma unroll
        for (int j = 0; j < 4; ++j)
            #pragma unroll
            for (int r = 0; r < 4; ++r) acc[i][j][r] = 0.0f;

    for (int k0 = 0; k0 < K; k0 += 32) {
        __syncthreads();                       // prev tile's ds_reads done
        gload_lds16(Ag0 + k0, Al0);
        gload_lds16(Ag1 + k0, Al1);
        gload_lds16(Bg0 + k0, Bl0);
        gload_lds16(Bg1 + k0, Bl1);
        __syncthreads();                       // drains vmcnt -> tile ready

        bf16x8 af[4], bfr[4];
        #pragma unroll
        for (int i = 0; i < 4; ++i)
            af[i] = *(const bf16x8*)&As[(wr + i * 16 + fr) * 32 + fk];
        #pragma unroll
        for (int j = 0; j < 4; ++j)
            bfr[j] = *(const bf16x8*)&Bs[(wc + j * 16 + fr) * 32 + fk];

        #pragma unroll
        for (int i = 0; i < 4; ++i)
            #pragma unroll
            for (int j = 0; j < 4; ++j)
                acc[i][j] = __builtin_amdgcn_mfma_f32_16x16x32_bf16(
                    af[i], bfr[j], acc[i][j], 0, 0, 0);
    }

    const int quad = lane >> 4;
    #pragma unroll
    for (int j = 0; j < 4; ++j) {
        const int col = col0 + wc + j * 16 + fr;
        const float bv = bias[col];
        #pragma unroll
        for (int i = 0; i < 4; ++i) {
            const int rowb = row0 + wr + i * 16 + quad * 4;
            #pragma unroll
            for (int r = 0; r < 4; ++r)
                C[(size_t)(rowb + r) * N + col] = acc[i][j][r] + bv;
        }
    }
}

// ---------------------------------------------------------------------------
// RoPE NeoX in-place on q (heads 0..35) and k (heads 36..39).
// ---------------------------------------------------------------------------
__global__ __launch_bounds__(64)
void rope_kernel(const int* __restrict__ positions, float* __restrict__ qkv)
{
    const int bh   = blockIdx.x;
    const int t    = bh / (NHEAD + NKVH);
    const int head = bh % (NHEAD + NKVH);
    const int d    = threadIdx.x;
    float* base = qkv + (size_t)t * NQKV +
                  ((head < NHEAD) ? head * HEADDIM : KOFF + (head - NHEAD) * HEADDIM);
    const float inv_freq = __expf(-(float)d * (11.512925465f / 64.0f)); // 1e5^(-d/64)
    const float ang = (float)positions[t] * inv_freq;
    float s, c;
    sincosf(ang, &s, &c);
    const float x1 = base[d];
    const float x2 = base[d + 64];
    base[d]      = x1 * c - x2 * s;
    base[d + 64] = x2 * c + x1 * s;
}

// ---------------------------------------------------------------------------
// MFMA flash attention (windowed causal GQA).
// Block: 256 thr = 4 waves; wave w owns q rows [q0+16w, q0+16w+16).
// Output written as bf16 (feeds GEMM2 A directly).
// ---------------------------------------------------------------------------
#define BQ 64
#define BS 32
#define KSTR 136
#define VSTR 40
#define PSTR 40

__global__ __launch_bounds__(256)
void attn_kernel(const float* __restrict__ qkv, __hip_bfloat16* __restrict__ out,
                 const int* __restrict__ windowp)
{
    __shared__ short Kh[BS * KSTR];                 // 8704 B
    __shared__ short Kl[BS * KSTR];                 // 8704 B
    __shared__ short Vt[HEADDIM * VSTR];            // 10240 B
    __shared__ __hip_bfloat16 Ps[4][16 * PSTR];     // 5120 B

    const int h    = blockIdx.x;
    const int q0   = blockIdx.y * BQ;
    const int kvh  = h / GQA_G;
    const int tid  = threadIdx.x;
    const int lane = tid & 63;
    const int wave = tid >> 6;
    const int l15  = lane & 15;
    const int quad = lane >> 4;
    const int window = *windowp;
    const float scale = 0.088388347648318447f;  // 1/sqrt(128)

    // ---- Q A-fragments (hi/lo split), scale folded; A row m = l15
    bf16x8 qh[4], ql[4];
    {
        const float* qp = qkv + (size_t)(q0 + wave * 16 + l15) * NQKV
                        + h * HEADDIM + quad * 8;
        #pragma unroll
        for (int ks = 0; ks < 4; ++ks) {
            union { bf16x8 v; __hip_bfloat16 x[8]; } H, L;
            #pragma unroll
            for (int j = 0; j < 8; ++j) {
                const float v = qp[ks * 32 + j] * scale;
                const __hip_bfloat16 hb = __float2bfloat16(v);
                H.x[j] = hb;
                L.x[j] = __float2bfloat16(v - __bfloat162float(hb));
            }
            qh[ks] = H.v; ql[ks] = L.v;
        }
    }

    f32x4 o[8];
    #pragma unroll
    for (int c = 0; c < 8; ++c)
        #pragma unroll
        for (int r = 0; r < 4; ++r) o[c][r] = 0.0f;
    float mrun[4], lrun[4];
    #pragma unroll
    for (int r = 0; r < 4; ++r) { mrun[r] = NEG_BIG; lrun[r] = 0.0f; }

    // staging maps
    const int ksr = tid >> 3;            // K row 0..31
    const int ksc = (tid & 7) * 16;      // K col base
    const int vcl = tid & 15;            // V col lane
    const int vr  = (tid >> 4) * 2;      // V row pair (even)

    int s_lo = q0 - window + 1;
    if (s_lo < 0) s_lo = 0;
    s_lo &= ~(BS - 1);

    __hip_bfloat16* Psw = &Ps[wave][0];

    for (int st = s_lo; st < q0 + BQ; st += BS) {
        __syncthreads();   // prev tile's Kh/Kl/Vt reads done
        // ---- stage K hi/lo
        {
            const float* kp = qkv + (size_t)(st + ksr) * NQKV + KOFF
                            + kvh * HEADDIM + ksc;
            float kf[16];
            *(float4*)&kf[0]  = *(const float4*)(kp);
            *(float4*)&kf[4]  = *(const float4*)(kp + 4);
            *(float4*)&kf[8]  = *(const float4*)(kp + 8);
            *(float4*)&kf[12] = *(const float4*)(kp + 12);
            union { bf16x8 v; __hip_bfloat16 x[8]; } H0, H1, L0, L1;
            #pragma unroll
            for (int j = 0; j < 8; ++j) {
                const __hip_bfloat16 h0 = __float2bfloat16(kf[j]);
                const __hip_bfloat16 h1 = __float2bfloat16(kf[8 + j]);
                H0.x[j] = h0; H1.x[j] = h1;
                L0.x[j] = __float2bfloat16(kf[j]     - __bfloat162float(h0));
                L1.x[j] = __float2bfloat16(kf[8 + j] - __bfloat162float(h1));
            }
            *(bf16x8*)&Kh[ksr * KSTR + ksc]     = H0.v;
            *(bf16x8*)&Kh[ksr * KSTR + ksc + 8] = H1.v;
            *(bf16x8*)&Kl[ksr * KSTR + ksc]     = L0.v;
            *(bf16x8*)&Kl[ksr * KSTR + ksc + 8] = L1.v;
        }
        // ---- stage V transposed: Vt[d][s]
        {
            const float* vp = qkv + (size_t)(st + vr) * NQKV + VOFF
                            + kvh * HEADDIM;
            #pragma unroll
            for (int i = 0; i < 8; ++i) {
                const int d = vcl + 16 * i;
                const float v0 = vp[d];
                const float v1 = vp[NQKV + d];
                *(__hip_bfloat162*)&Vt[d * VSTR + vr] =
                    __float22bfloat162_rn(make_float2(v0, v1));
            }
        }
        __syncthreads();

        // ---- S = Q K^T  (two 16x16 subtiles over s)
        f32x4 acc0, acc1;
        #pragma unroll
        for (int r = 0; r < 4; ++r) { acc0[r] = 0.0f; acc1[r] = 0.0f; }
        #pragma unroll
        for (int ks = 0; ks < 4; ++ks) {
            const int ko = ks * 32 + quad * 8;
            const bf16x8 bh0 = *(const bf16x8*)&Kh[l15 * KSTR + ko];
            const bf16x8 bl0 = *(const bf16x8*)&Kl[l15 * KSTR + ko];
            const bf16x8 bh1 = *(const bf16x8*)&Kh[(16 + l15) * KSTR + ko];
            const bf16x8 bl1 = *(const bf16x8*)&Kl[(16 + l15) * KSTR + ko];
            acc0 = __builtin_amdgcn_mfma_f32_16x16x32_bf16(qh[ks], bh0, acc0, 0, 0, 0);
            acc1 = __builtin_amdgcn_mfma_f32_16x16x32_bf16(qh[ks], bh1, acc1, 0, 0, 0);
            acc0 = __builtin_amdgcn_mfma_f32_16x16x32_bf16(ql[ks], bh0, acc0, 0, 0, 0);
            acc1 = __builtin_amdgcn_mfma_f32_16x16x32_bf16(ql[ks], bh1, acc1, 0, 0, 0);
            acc0 = __builtin_amdgcn_mfma_f32_16x16x32_bf16(qh[ks], bl0, acc0, 0, 0, 0);
            acc1 = __builtin_amdgcn_mfma_f32_16x16x32_bf16(qh[ks], bl1, acc1, 0, 0, 0);
        }

        // ---- mask + online softmax on C-layout (row=quad*4+r, col=l15)
        const int qb  = q0 + wave * 16 + quad * 4;
        const int s0g = st + l15;
        const int s1g = st + 16 + l15;
        #pragma unroll
        for (int r = 0; r < 4; ++r) {
            const int q = qb + r;
            const bool v0 = (s0g <= q) && (s0g > q - window);
            const bool v1 = (s1g <= q) && (s1g > q - window);
            float a = v0 ? acc0[r] : NEG_BIG;
            float b = v1 ? acc1[r] : NEG_BIG;
            float mx = fmaxf(a, b);
            mx = fmaxf(mx, __shfl_xor(mx, 1));
            mx = fmaxf(mx, __shfl_xor(mx, 2));
            mx = fmaxf(mx, __shfl_xor(mx, 4));
            mx = fmaxf(mx, __shfl_xor(mx, 8));
            mx = fmaxf(mrun[r], mx);
            const float alpha = __expf(mrun[r] - mx);   // 1 while all-masked
            mrun[r] = mx;
            const float e0 = v0 ? __expf(acc0[r] - mx) : 0.0f;
            const float e1 = v1 ? __expf(acc1[r] - mx) : 0.0f;
            const __hip_bfloat162 pp = __float22bfloat162_rn(make_float2(e0, e1));
            Psw[(quad * 4 + r) * PSTR + l15]      = pp.x;
            Psw[(quad * 4 + r) * PSTR + 16 + l15] = pp.y;
            float sum = __bfloat162float(pp.x) + __bfloat162float(pp.y);
            sum += __shfl_xor(sum, 1);
            sum += __shfl_xor(sum, 2);
            sum += __shfl_xor(sum, 4);
            sum += __shfl_xor(sum, 8);
            lrun[r] = lrun[r] * alpha + sum;
            #pragma unroll
            for (int c = 0; c < 8; ++c) o[c][r] *= alpha;
        }

        // ---- PV: A = P (A-layout from LDS), B = Vt rows (n=d)
        const bf16x8 pa = *(const bf16x8*)&Psw[l15 * PSTR + quad * 8];
        #pragma unroll
        for (int c = 0; c < 8; ++c) {
            const bf16x8 vb = *(const bf16x8*)&Vt[(16 * c + l15) * VSTR + quad * 8];
            o[c] = __builtin_amdgcn_mfma_f32_16x16x32_bf16(pa, vb, o[c], 0, 0, 0);
        }
    }

    // ---- epilogue: normalize, write bf16 out[q][h*128 + d]
    #pragma unroll
    for (int r = 0; r < 4; ++r) {
        const float inv = 1.0f / lrun[r];   // diagonal always valid
        __hip_bfloat16* op = out
                  + (size_t)(q0 + wave * 16 + quad * 4 + r) * (NHEAD * HEADDIM)
                  + h * HEADDIM + l15;
        #pragma unroll
        for (int c = 0; c < 8; ++c) op[16 * c] = __float2bfloat16(o[c][r] * inv);
    }
}

// ---------------------------------------------------------------------------
extern "C" void kernel_launch(void* const* d_in, const int* in_sizes, int n_in,
                              void* d_out, int out_size, void* d_ws, size_t ws_size,
                              hipStream_t stream)
{
    const int*   positions = (const int*)d_in[0];
    const float* hidden    = (const float*)d_in[1];
    const float* wqkv      = (const float*)d_in[2];
    const float* bqkv      = (const float*)d_in[3];
    const float* wo        = (const float*)d_in[4];
    const float* bo        = (const float*)d_in[5];
    const int*   windowp   = (const int*)d_in[6];
    float* outp = (float*)d_out;

    // ws layout:
    //   qkv   fp32 [T,5632]      46.1 MB
    //   hbf   bf16 [T,4608]      18.9 MB
    //   wqbf  bf16 [5632,4608]   51.9 MB
    //   wobf  bf16 [4608,4608]   42.5 MB
    //   abf   bf16 [T,4608]      18.9 MB    (attn output)
    float* qkv = (float*)d_ws;
    __hip_bfloat16* hbf  = (__hip_bfloat16*)(qkv + (size_t)T_SEQ * NQKV);
    __hip_bfloat16* wqbf = hbf  + (size_t)T_SEQ * HIDDEN;
    __hip_bfloat16* wobf = wqbf + (size_t)NQKV * HIDDEN;
    __hip_bfloat16* abf  = wobf + (size_t)HIDDEN * HIDDEN;

    cvt_bf16_kernel<<<1024, 256, 0, stream>>>(hidden, hbf, T_SEQ * HIDDEN / 8);
    cvt_bf16_kernel<<<2048, 256, 0, stream>>>(wqkv, wqbf, NQKV * HIDDEN / 8);
    cvt_bf16_kernel<<<2048, 256, 0, stream>>>(wo, wobf, HIDDEN * HIDDEN / 8);

    gemm_bf16bt_kernel<<<dim3(NQKV / 128, T_SEQ / 128), 256, 0, stream>>>(
        hbf, wqbf, bqkv, qkv, NQKV, HIDDEN);

    rope_kernel<<<T_SEQ * (NHEAD + NKVH), 64, 0, stream>>>(positions, qkv);

    attn_kernel<<<dim3(NHEAD, T_SEQ / BQ), 256, 0, stream>>>(qkv, abf, windowp);

    gemm_bf16bt_kernel<<<dim3(HIDDEN / 128, T_SEQ / 128), 256, 0, stream>>>(
        abf, wobf, bo, outp, HIDDEN, HIDDEN);
}

// Round 2
// 717.834 us; speedup vs baseline: 1.1346x; 1.0575x over previous
//
#include <hip/hip_runtime.h>
#include <hip/hip_bf16.h>
#include <math.h>

// Starcoder2 attention R6:
//  - NEW prep_kv kernel: one-shot RoPE(K) + hi/lo bf16 split + V transpose,
//    stored per-32-key-tile as 8KB LDS images in "granule-major" order:
//      K image:  [gd=d/8][s][j]  (gd 0..15, s 0..31, j 0..7)
//      V image:  [q=s/8][d][j]   (q 0..3, d 0..127, j=s%8)
//    so fragment ds_read_b128s are lane-contiguous (8 lanes per 4-bank group
//    = conflict-free) and a LINEAR global_load_lds reproduces the layout.
//  - attn: K/V staged via 6x global_load_lds dwordx4 per wave (zero VALU),
//    double-buffered 2-phase (stage next || compute current, one
//    vmcnt(0)+barrier per tile). RoPE(Q) applied in-register (lane's 32
//    d-values are closed under the d<->d+64 NeoX pairing). rope_kernel gone.
//  - GEMMs / cvt unchanged from verified R5 (m97 global_load_lds structure).
// T=2048, HID=4608, H=36, KV=4, D=128, window=1024.

#define T_SEQ   2048
#define HIDDEN  4608
#define NHEAD   36
#define NKVH    4
#define HEADDIM 128
#define GQA_G   9
#define NQKV    5632
#define KOFF    4608
#define VOFF    5120
#define NEG_BIG -1e30f
#define BQ 64
#define BS 32
#define NTILE   64            // T_SEQ / BS
#define PSTR 40

typedef short bf16x8 __attribute__((ext_vector_type(8)));
typedef float f32x4  __attribute__((ext_vector_type(4)));

// pack 8 fp32 -> 8 bf16 (RNE)
__device__ inline bf16x8 pack8(float4 u, float4 v) {
    union { bf16x8 v8; __hip_bfloat162 h[4]; } r;
    r.h[0] = __float22bfloat162_rn(make_float2(u.x, u.y));
    r.h[1] = __float22bfloat162_rn(make_float2(u.z, u.w));
    r.h[2] = __float22bfloat162_rn(make_float2(v.x, v.y));
    r.h[3] = __float22bfloat162_rn(make_float2(v.z, v.w));
    return r.v8;
}

// async global->LDS, 16 B per lane. LDS dest wave-uniform; lane l lands at
// ldsbase + l*16; global source address is per-lane.
typedef const __attribute__((address_space(1))) int* gas_ptr;
typedef __attribute__((address_space(3))) int*       las_ptr;
__device__ __forceinline__ void gload_lds16(const void* g, void* l) {
    __builtin_amdgcn_global_load_lds((gas_ptr)g, (las_ptr)l, 16, 0, 0);
}

// ---------------------------------------------------------------------------
// fp32 -> bf16 conversion (memory-bound, vectorized 8 elems/thread/iter)
// ---------------------------------------------------------------------------
__global__ __launch_bounds__(256)
void cvt_bf16_kernel(const float* __restrict__ in, __hip_bfloat16* __restrict__ out,
                     int n8)
{
    for (int i = blockIdx.x * 256 + threadIdx.x; i < n8; i += gridDim.x * 256) {
        const float4 a = *(const float4*)(in + (size_t)i * 8);
        const float4 b = *(const float4*)(in + (size_t)i * 8 + 4);
        *(bf16x8*)(out + (size_t)i * 8) = pack8(a, b);
    }
}

// ---------------------------------------------------------------------------
// GEMM: C[M,N](fp32) = A[M,K](bf16) @ B[N,K](bf16)^T + bias
// 128x128 tile, BK=32, 4 waves, global_load_lds staging (m97 structure).
// ---------------------------------------------------------------------------
__global__ __launch_bounds__(256)
void gemm_bf16bt_kernel(const __hip_bfloat16* __restrict__ A,
                        const __hip_bfloat16* __restrict__ B,
                        const float* __restrict__ bias,
                        float* __restrict__ C, int N, int K)
{
    __shared__ short As[128 * 32];   // 8 KB, row-major [row][k], 64 B rows
    __shared__ short Bs[128 * 32];   // 8 KB

    const int tid  = threadIdx.x;
    const int lane = tid & 63;
    const int wave = tid >> 6;
    const int row0 = blockIdx.y * 128;
    const int col0 = blockIdx.x * 128;
    const int wr   = (wave >> 1) * 64;
    const int wc   = (wave & 1) * 64;
    const int fr   = lane & 15;
    const int fk   = (lane >> 4) * 8;

    const int srow = lane >> 2;
    const int scol = (lane & 3) * 8;

    const __hip_bfloat16* Ag0 = A + (size_t)(row0 + wave * 32 + srow) * K + scol;
    const __hip_bfloat16* Ag1 = Ag0 + (size_t)16 * K;
    const __hip_bfloat16* Bg0 = B + (size_t)(col0 + wave * 32 + srow) * K + scol;
    const __hip_bfloat16* Bg1 = Bg0 + (size_t)16 * K;

    short* Al0 = &As[(wave * 32) * 32];
    short* Al1 = &As[(wave * 32 + 16) * 32];
    short* Bl0 = &Bs[(wave * 32) * 32];
    short* Bl1 = &Bs[(wave * 32 + 16) * 32];

    f32x4 acc[4][4];
    #pragma unroll
    for (int i = 0; i < 4; ++i)
        #pragma unroll
        for (int j = 0; j < 4; ++j)
            #pragma unroll
            for (int r = 0; r < 4; ++r) acc[i][j][r] = 0.0f;

    for (int k0 = 0; k0 < K; k0 += 32) {
        __syncthreads();
        gload_lds16(Ag0 + k0, Al0);
        gload_lds16(Ag1 + k0, Al1);
        gload_lds16(Bg0 + k0, Bl0);
        gload_lds16(Bg1 + k0, Bl1);
        __syncthreads();

        bf16x8 af[4], bfr[4];
        #pragma unroll
        for (int i = 0; i < 4; ++i)
            af[i] = *(const bf16x8*)&As[(wr + i * 16 + fr) * 32 + fk];
        #pragma unroll
        for (int j = 0; j < 4; ++j)
            bfr[j] = *(const bf16x8*)&Bs[(wc + j * 16 + fr) * 32 + fk];

        #pragma unroll
        for (int i = 0; i < 4; ++i)
            #pragma unroll
            for (int j = 0; j < 4; ++j)
                acc[i][j] = __builtin_amdgcn_mfma_f32_16x16x32_bf16(
                    af[i], bfr[j], acc[i][j], 0, 0, 0);
    }

    const int quad = lane >> 4;
    #pragma unroll
    for (int j = 0; j < 4; ++j) {
        const int col = col0 + wc + j * 16 + fr;
        const float bv = bias[col];
        #pragma unroll
        for (int i = 0; i < 4; ++i) {
            const int rowb = row0 + wr + i * 16 + quad * 4;
            #pragma unroll
            for (int r = 0; r < 4; ++r)
                C[(size_t)(rowb + r) * N + col] = acc[i][j][r] + bv;
        }
    }
}

// ---------------------------------------------------------------------------
// prep_kv: per (tile, kvh) build the three 8KB LDS images:
//   Kh/Kl image [gd][s][j]: RoPE'd K, hi/lo bf16 split  (gd=d/8, j=d%8)
//   Vt image    [q][d][j] : V transposed bf16           (q=s/8,  j=s%8)
// grid (NTILE, NKVH) x 256 threads.
// ---------------------------------------------------------------------------
__global__ __launch_bounds__(256)
void prep_kv_kernel(const int* __restrict__ positions,
                    const float* __restrict__ qkv,
                    __hip_bfloat16* __restrict__ Kht,
                    __hip_bfloat16* __restrict__ Klt,
                    __hip_bfloat16* __restrict__ Vtt)
{
    const int tile = blockIdx.x;
    const int kvh  = blockIdx.y;
    const int t    = threadIdx.x;
    const size_t ib = ((size_t)kvh * NTILE + tile) * 4096;

    // ---- K: thread -> row s = t>>3, d-halfpair base j8 = (t&7)*8
    {
        const int s   = t >> 3;
        const int j8  = (t & 7) * 8;
        const int row = tile * BS + s;
        const float* kp = qkv + (size_t)row * NQKV + KOFF + kvh * HEADDIM;
        float x1[8], x2[8];
        *(float4*)&x1[0] = *(const float4*)(kp + j8);
        *(float4*)&x1[4] = *(const float4*)(kp + j8 + 4);
        *(float4*)&x2[0] = *(const float4*)(kp + 64 + j8);
        *(float4*)&x2[4] = *(const float4*)(kp + 64 + j8 + 4);
        const float pos = (float)positions[row];
        union { bf16x8 v; __hip_bfloat16 x[8]; } H1, L1, H2, L2;
        #pragma unroll
        for (int j = 0; j < 8; ++j) {
            const int d = j8 + j;
            const float inv_freq = __expf(-(float)d * (11.512925465f / 64.0f));
            float sn, cs;
            sincosf(pos * inv_freq, &sn, &cs);
            const float r1 = x1[j] * cs - x2[j] * sn;
            const float r2 = x2[j] * cs + x1[j] * sn;
            const __hip_bfloat16 h1 = __float2bfloat16(r1);
            const __hip_bfloat16 h2 = __float2bfloat16(r2);
            H1.x[j] = h1; L1.x[j] = __float2bfloat16(r1 - __bfloat162float(h1));
            H2.x[j] = h2; L2.x[j] = __float2bfloat16(r2 - __bfloat162float(h2));
        }
        const int gd1 = (t & 7);       // d in [0,64)
        const int gd2 = gd1 + 8;       // d+64
        *(bf16x8*)&Kht[ib + gd1 * 256 + s * 8] = H1.v;
        *(bf16x8*)&Kht[ib + gd2 * 256 + s * 8] = H2.v;
        *(bf16x8*)&Klt[ib + gd1 * 256 + s * 8] = L1.v;
        *(bf16x8*)&Klt[ib + gd2 * 256 + s * 8] = L2.v;
    }

    // ---- V: thread -> q = t>>6, d-pair d0 = (t&63)*2
    {
        const int q  = t >> 6;
        const int d0 = (t & 63) * 2;
        const float* vp = qkv + (size_t)(tile * BS + q * 8) * NQKV + VOFF
                        + kvh * HEADDIM + d0;
        union { bf16x8 v; __hip_bfloat16 x[8]; } V0, V1;
        #pragma unroll
        for (int j = 0; j < 8; ++j) {
            const float2 vv = *(const float2*)(vp + (size_t)j * NQKV);
            const __hip_bfloat162 pb = __float22bfloat162_rn(make_float2(vv.x, vv.y));
            V0.x[j] = pb.x;
            V1.x[j] = pb.y;
        }
        *(bf16x8*)&Vtt[ib + q * 1024 + d0 * 8]       = V0.v;
        *(bf16x8*)&Vtt[ib + q * 1024 + (d0 + 1) * 8] = V1.v;
    }
}

// ---------------------------------------------------------------------------
// MFMA flash attention (windowed causal GQA), R6:
// K/V staged from precomputed tile images via global_load_lds, 2-phase
// double buffer. RoPE(Q) in-register. Output bf16.
// ---------------------------------------------------------------------------
__global__ __launch_bounds__(256)
void attn_kernel(const float* __restrict__ qkv,
                 const int* __restrict__ positions,
                 const __hip_bfloat16* __restrict__ Kht,
                 const __hip_bfloat16* __restrict__ Klt,
                 const __hip_bfloat16* __restrict__ Vtt,
                 __hip_bfloat16* __restrict__ out,
                 const int* __restrict__ windowp)
{
    __shared__ short KhS[2][4096];                  // 16 KB
    __shared__ short KlS[2][4096];                  // 16 KB
    __shared__ short VtS[2][4096];                  // 16 KB
    __shared__ __hip_bfloat16 Ps[4][16 * PSTR];     // 5 KB   (total 54272 B)

    const int h    = blockIdx.x;
    const int q0   = blockIdx.y * BQ;
    const int kvh  = h / GQA_G;
    const int tid  = threadIdx.x;
    const int lane = tid & 63;
    const int wave = tid >> 6;
    const int l15  = lane & 15;
    const int quad = lane >> 4;
    const int window = *windowp;
    const float scale = 0.088388347648318447f;  // 1/sqrt(128)

    // ---- Q load + in-register RoPE + scale + hi/lo split; A row m = l15
    bf16x8 qh[4], ql[4];
    {
        const int qrow = q0 + wave * 16 + l15;
        const float* qp = qkv + (size_t)qrow * NQKV + h * HEADDIM + quad * 8;
        float qv[32];                         // [ks*8+j] = Q[d = ks*32+quad*8+j]
        #pragma unroll
        for (int ks = 0; ks < 4; ++ks) {
            *(float4*)&qv[ks * 8]     = *(const float4*)(qp + ks * 32);
            *(float4*)&qv[ks * 8 + 4] = *(const float4*)(qp + ks * 32 + 4);
        }
        const float pos = (float)positions[qrow];
        #pragma unroll
        for (int p = 0; p < 2; ++p)
            #pragma unroll
            for (int j = 0; j < 8; ++j) {
                const int d = p * 32 + quad * 8 + j;       // < 64
                const float inv_freq = __expf(-(float)d * (11.512925465f / 64.0f));
                float sn, cs;
                sincosf(pos * inv_freq, &sn, &cs);
                const float x1 = qv[p * 8 + j];            // d
                const float x2 = qv[(p + 2) * 8 + j];      // d+64
                qv[p * 8 + j]       = x1 * cs - x2 * sn;
                qv[(p + 2) * 8 + j] = x2 * cs + x1 * sn;
            }
        #pragma unroll
        for (int ks = 0; ks < 4; ++ks) {
            union { bf16x8 v; __hip_bfloat16 x[8]; } H, L;
            #pragma unroll
            for (int j = 0; j < 8; ++j) {
                const float v = qv[ks * 8 + j] * scale;
                const __hip_bfloat16 hb = __float2bfloat16(v);
                H.x[j] = hb;
                L.x[j] = __float2bfloat16(v - __bfloat162float(hb));
            }
            qh[ks] = H.v; ql[ks] = L.v;
        }
    }

    f32x4 o[8];
    #pragma unroll
    for (int c = 0; c < 8; ++c)
        #pragma unroll
        for (int r = 0; r < 4; ++r) o[c][r] = 0.0f;
    float mrun[4], lrun[4];
    #pragma unroll
    for (int r = 0; r < 4; ++r) { mrun[r] = NEG_BIG; lrun[r] = 0.0f; }

    int s_lo = q0 - window + 1;
    if (s_lo < 0) s_lo = 0;
    s_lo &= ~(BS - 1);
    const int tile0  = s_lo >> 5;
    const int ntiles = ((q0 + BQ) - s_lo) >> 5;

    const short* gKh = (const short*)Kht + ((size_t)kvh * NTILE) * 4096;
    const short* gKl = (const short*)Klt + ((size_t)kvh * NTILE) * 4096;
    const short* gVt = (const short*)Vtt + ((size_t)kvh * NTILE) * 4096;

    __hip_bfloat16* Psw = &Ps[wave][0];

    // per-wave stage of one tile's three 8KB images (2 x 1KB chunks each)
    auto STAGE = [&](int buf, int tile) {
        const size_t toff = (size_t)tile * 4096;
        #pragma unroll
        for (int i = 0; i < 2; ++i) {
            const int o = (wave * 2 + i) * 512;          // shorts
            gload_lds16(gKh + toff + o + lane * 8, &KhS[buf][o]);
            gload_lds16(gKl + toff + o + lane * 8, &KlS[buf][o]);
            gload_lds16(gVt + toff + o + lane * 8, &VtS[buf][o]);
        }
    };

    STAGE(0, tile0);
    __syncthreads();                       // drains vmcnt -> buf0 ready
    int cur = 0;

    for (int it = 0; it < ntiles; ++it) {
        const int st = s_lo + it * BS;
        if (it + 1 < ntiles) STAGE(cur ^ 1, tile0 + it + 1);   // prefetch

        // ---- S = Q K^T  (two 16x16 subtiles over s)
        f32x4 acc0, acc1;
        #pragma unroll
        for (int r = 0; r < 4; ++r) { acc0[r] = 0.0f; acc1[r] = 0.0f; }
        #pragma unroll
        for (int ks = 0; ks < 4; ++ks) {
            const int g = (ks * 4 + quad) * 256;         // granule gd = d/8
            const bf16x8 bh0 = *(const bf16x8*)&KhS[cur][g + l15 * 8];
            const bf16x8 bl0 = *(const bf16x8*)&KlS[cur][g + l15 * 8];
            const bf16x8 bh1 = *(const bf16x8*)&KhS[cur][g + (16 + l15) * 8];
            const bf16x8 bl1 = *(const bf16x8*)&KlS[cur][g + (16 + l15) * 8];
            acc0 = __builtin_amdgcn_mfma_f32_16x16x32_bf16(qh[ks], bh0, acc0, 0, 0, 0);
            acc1 = __builtin_amdgcn_mfma_f32_16x16x32_bf16(qh[ks], bh1, acc1, 0, 0, 0);
            acc0 = __builtin_amdgcn_mfma_f32_16x16x32_bf16(ql[ks], bh0, acc0, 0, 0, 0);
            acc1 = __builtin_amdgcn_mfma_f32_16x16x32_bf16(ql[ks], bh1, acc1, 0, 0, 0);
            acc0 = __builtin_amdgcn_mfma_f32_16x16x32_bf16(qh[ks], bl0, acc0, 0, 0, 0);
            acc1 = __builtin_amdgcn_mfma_f32_16x16x32_bf16(qh[ks], bl1, acc1, 0, 0, 0);
        }

        // ---- mask + online softmax on C-layout (row=quad*4+r, col=l15)
        const int qb  = q0 + wave * 16 + quad * 4;
        const int s0g = st + l15;
        const int s1g = st + 16 + l15;
        #pragma unroll
        for (int r = 0; r < 4; ++r) {
            const int q = qb + r;
            const bool v0 = (s0g <= q) && (s0g > q - window);
            const bool v1 = (s1g <= q) && (s1g > q - window);
            float a = v0 ? acc0[r] : NEG_BIG;
            float b = v1 ? acc1[r] : NEG_BIG;
            float mx = fmaxf(a, b);
            mx = fmaxf(mx, __shfl_xor(mx, 1));
            mx = fmaxf(mx, __shfl_xor(mx, 2));
            mx = fmaxf(mx, __shfl_xor(mx, 4));
            mx = fmaxf(mx, __shfl_xor(mx, 8));
            mx = fmaxf(mrun[r], mx);
            const float alpha = __expf(mrun[r] - mx);   // 1 while all-masked
            mrun[r] = mx;
            const float e0 = v0 ? __expf(acc0[r] - mx) : 0.0f;
            const float e1 = v1 ? __expf(acc1[r] - mx) : 0.0f;
            const __hip_bfloat162 pp = __float22bfloat162_rn(make_float2(e0, e1));
            Psw[(quad * 4 + r) * PSTR + l15]      = pp.x;
            Psw[(quad * 4 + r) * PSTR + 16 + l15] = pp.y;
            float sum = __bfloat162float(pp.x) + __bfloat162float(pp.y);
            sum += __shfl_xor(sum, 1);
            sum += __shfl_xor(sum, 2);
            sum += __shfl_xor(sum, 4);
            sum += __shfl_xor(sum, 8);
            lrun[r] = lrun[r] * alpha + sum;
            #pragma unroll
            for (int c = 0; c < 8; ++c) o[c][r] *= alpha;
        }

        // ---- PV: A = P (A-layout from per-wave LDS), B = Vt image rows
        const bf16x8 pa = *(const bf16x8*)&Psw[l15 * PSTR + quad * 8];
        #pragma unroll
        for (int c = 0; c < 8; ++c) {
            const bf16x8 vb = *(const bf16x8*)&VtS[cur][quad * 1024 + (16 * c + l15) * 8];
            o[c] = __builtin_amdgcn_mfma_f32_16x16x32_bf16(pa, vb, o[c], 0, 0, 0);
        }

        __syncthreads();    // drains vmcnt (prefetch landed) + buf reuse fence
        cur ^= 1;
    }

    // ---- epilogue: normalize, write bf16 out[q][h*128 + d]
    #pragma unroll
    for (int r = 0; r < 4; ++r) {
        const float inv = 1.0f / lrun[r];   // diagonal always valid
        __hip_bfloat16* op = out
                  + (size_t)(q0 + wave * 16 + quad * 4 + r) * (NHEAD * HEADDIM)
                  + h * HEADDIM + l15;
        #pragma unroll
        for (int c = 0; c < 8; ++c) op[16 * c] = __float2bfloat16(o[c][r] * inv);
    }
}

// ---------------------------------------------------------------------------
extern "C" void kernel_launch(void* const* d_in, const int* in_sizes, int n_in,
                              void* d_out, int out_size, void* d_ws, size_t ws_size,
                              hipStream_t stream)
{
    const int*   positions = (const int*)d_in[0];
    const float* hidden    = (const float*)d_in[1];
    const float* wqkv      = (const float*)d_in[2];
    const float* bqkv      = (const float*)d_in[3];
    const float* wo        = (const float*)d_in[4];
    const float* bo        = (const float*)d_in[5];
    const int*   windowp   = (const int*)d_in[6];
    float* outp = (float*)d_out;

    // ws layout:
    //   qkv   fp32 [T,5632]      46.1 MB
    //   hbf   bf16 [T,4608]      18.9 MB
    //   wqbf  bf16 [5632,4608]   51.9 MB
    //   wobf  bf16 [4608,4608]   42.5 MB
    //   abf   bf16 [T,4608]      18.9 MB
    //   Kht/Klt/Vtt bf16 tile images  3 x 2.0 MB
    float* qkv = (float*)d_ws;
    __hip_bfloat16* hbf  = (__hip_bfloat16*)(qkv + (size_t)T_SEQ * NQKV);
    __hip_bfloat16* wqbf = hbf  + (size_t)T_SEQ * HIDDEN;
    __hip_bfloat16* wobf = wqbf + (size_t)NQKV * HIDDEN;
    __hip_bfloat16* abf  = wobf + (size_t)HIDDEN * HIDDEN;
    __hip_bfloat16* Kht  = abf  + (size_t)T_SEQ * HIDDEN;
    __hip_bfloat16* Klt  = Kht  + (size_t)NKVH * NTILE * 4096;
    __hip_bfloat16* Vtt  = Klt  + (size_t)NKVH * NTILE * 4096;

    cvt_bf16_kernel<<<1024, 256, 0, stream>>>(hidden, hbf, T_SEQ * HIDDEN / 8);
    cvt_bf16_kernel<<<2048, 256, 0, stream>>>(wqkv, wqbf, NQKV * HIDDEN / 8);
    cvt_bf16_kernel<<<2048, 256, 0, stream>>>(wo, wobf, HIDDEN * HIDDEN / 8);

    gemm_bf16bt_kernel<<<dim3(NQKV / 128, T_SEQ / 128), 256, 0, stream>>>(
        hbf, wqbf, bqkv, qkv, NQKV, HIDDEN);

    prep_kv_kernel<<<dim3(NTILE, NKVH), 256, 0, stream>>>(
        positions, qkv, Kht, Klt, Vtt);

    attn_kernel<<<dim3(NHEAD, T_SEQ / BQ), 256, 0, stream>>>(
        qkv, positions, Kht, Klt, Vtt, abf, windowp);

    gemm_bf16bt_kernel<<<dim3(HIDDEN / 128, T_SEQ / 128), 256, 0, stream>>>(
        abf, wobf, bo, outp, HIDDEN, HIDDEN);
}